// Round 3
// baseline (447.499 us; speedup 1.0000x reference)
//
#include <hip/hip_runtime.h>
#include <hip/hip_cooperative_groups.h>
#include <stdint.h>

namespace cg = cooperative_groups;

typedef __attribute__((ext_vector_type(8))) short short8;
typedef __attribute__((ext_vector_type(4))) float floatx4;

static inline size_t align256(size_t x) { return (x + 255) & ~size_t(255); }

__device__ __forceinline__ unsigned short f2bf(float f) {
    unsigned u = __float_as_uint(f);
    u += 0x7fff + ((u >> 16) & 1);     // round-to-nearest-even
    return (unsigned short)(u >> 16);
}
__device__ __forceinline__ unsigned pack_bf16(float a, float b) {
    return (unsigned)f2bf(a) | ((unsigned)f2bf(b) << 16);
}
__device__ __forceinline__ float bf_lo(unsigned u) { return __uint_as_float(u << 16); }
__device__ __forceinline__ float bf_hi(unsigned u) { return __uint_as_float(u & 0xffff0000u); }

#define BSHIFT 7     // 128 nodes per dst-bucket
#define NBMAX 1024   // max buckets per LDS window (fallback kernels)
#define CH 2048      // edges per chunk
#define SCAP 3072    // LDS-staged pairs per bucket
#define SHW 3328     // shared scratch ints in k_csr (13 KB)
// bbuf packing: (dst&127)<<25 | src  -- requires N < 2^25 (here N=50000)

// per-block edge dtype self-detection: int32 data read as int64 pairs gives
// out-of-range values with prob ~1 per sample; 256 samples => certain.
__device__ __forceinline__ bool detect_i32(const void* eidx, int E, int t) {
    const long long* e64 = (const long long*)eidx;
    int nchk = E < 256 ? E : 256;
    long long v = e64[t % nchk];
    int bad = (v < 0 || v > 0x7fffffffLL) ? 1 : 0;
    return __syncthreads_or(bad) != 0;
}

// 256-thread exclusive scan helper; sw = 4-int LDS scratch. Returns this
// thread's exclusive prefix; *tot = block total. Safe to call in a loop.
__device__ __forceinline__ int blockScanExcl(int v, int t, int* sw, int* tot) {
    int lane = t & 63, w = t >> 6;
    int incl = v;
    #pragma unroll
    for (int off = 1; off < 64; off <<= 1) {
        int nbr = __shfl_up(incl, off, 64);
        if (lane >= off) incl += nbr;
    }
    if (lane == 63) sw[w] = incl;
    __syncthreads();
    int woff = 0;
    for (int j = 0; j < w; ++j) woff += sw[j];
    int tt = sw[0] + sw[1] + sw[2] + sw[3];
    __syncthreads();
    *tot = tt;
    return woff + incl - v;
}

// ============================================================================
// Cooperative CSR build: hist -> btot -> bscan -> hscan2 -> bfill -> sort
// in ONE dispatch (grid = max(NB,NC) blocks x 256), grid.sync() between phases.
// Writes stay LDS-binned/coalesced (the R2 atomic-scatter k_fill caused 17x
// HBM write amplification: 4B random scatter from 8 non-coherent XCD L2s).
// ============================================================================
__global__ __launch_bounds__(256, 2) void k_csr(
        const void* __restrict__ eidx, int E, int N, int NB, int NC,
        int* __restrict__ chist, int* __restrict__ btot, int* __restrict__ bbase,
        int* __restrict__ rs, float* __restrict__ dinv,
        unsigned* __restrict__ bbuf, int* __restrict__ esrc,
        const float* __restrict__ W1, const float* __restrict__ W2,
        unsigned short* __restrict__ w1t, unsigned short* __restrict__ w2t,
        int K1, int M1, int K2, int M2) {
    cg::grid_group grid = cg::this_grid();
    __shared__ int sh[SHW];
    __shared__ int sw[4];
    const int t = threadIdx.x, B = blockIdx.x;
    const int gid = B * 256 + t, gtot = gridDim.x * 256;
    const bool i32 = detect_i32(eidx, E, t);
    const int* e32 = (const int*)eidx;
    const long long* e64 = (const long long*)eidx;

    // ---- phase A: per-chunk histogram + weight transposes ----
    if (B < NC) {
        const int e0 = B * CH;
        const int e1 = (e0 + CH < E) ? e0 + CH : E;
        for (int b0 = 0; b0 < NB; b0 += SHW) {
            int bw = (NB - b0 < SHW) ? NB - b0 : SHW;
            for (int i = t; i < bw; i += 256) sh[i] = 0;
            __syncthreads();
            for (int e = e0 + t; e < e1; e += 256) {
                int d = i32 ? e32[(size_t)E + e] : (int)e64[(size_t)E + e];
                int b = (d >> BSHIFT) - b0;
                if (b >= 0 && b < bw) atomicAdd(&sh[b], 1);
            }
            __syncthreads();
            for (int i = t; i < bw; i += 256) chist[(size_t)(b0 + i) * NC + B] = sh[i];
            __syncthreads();
        }
    }
    for (int j = gid; j < K1 * M1; j += gtot) {
        int k = j / M1, n = j % M1;
        w1t[(size_t)n * K1 + k] = f2bf(W1[j]);
    }
    for (int j = gid; j < K2 * M2; j += gtot) {
        int k = j / M2, n = j % M2;
        w2t[(size_t)n * K2 + k] = f2bf(W2[j]);
    }
    grid.sync();

    // ---- phase B: bucket totals (block B sums chist row B) ----
    if (B < NB) {
        const int* row = chist + (size_t)B * NC;
        int v = 0;
        for (int i = t; i < NC; i += 256) v += row[i];
        int lane = t & 63, w = t >> 6;
        #pragma unroll
        for (int off = 32; off >= 1; off >>= 1) v += __shfl_xor(v, off, 64);
        if (lane == 0) sw[w] = v;
        __syncthreads();
        if (t == 0) btot[B] = sw[0] + sw[1] + sw[2] + sw[3];
    }
    grid.sync();

    // ---- phase C: block 0 exclusive-scans btot -> bbase ----
    if (B == 0) {
        int carry = 0;
        for (int base = 0; base < NB; base += 256) {
            int i = base + t;
            int v = (i < NB) ? btot[i] : 0;
            int tot;
            int ex = blockScanExcl(v, t, sw, &tot);
            if (i < NB) bbase[i] = carry + ex;
            carry += tot;
        }
        if (t == 0) { bbase[NB] = carry; rs[N] = carry; }
    }
    grid.sync();

    // ---- phase D: per-bucket chunk scan seeded with bbase ----
    if (B < NB) {
        int* row = chist + (size_t)B * NC;
        int carry = bbase[B];
        for (int base = 0; base < NC; base += 256) {
            int i = base + t;
            int v = (i < NC) ? row[i] : 0;
            int tot;
            int ex = blockScanExcl(v, t, sw, &tot);
            if (i < NC) row[i] = carry + ex;
            carry += tot;
        }
    }
    grid.sync();

    // ---- phase E: binned fill (LDS rank), packed payload ----
    if (B < NC) {
        const int e0 = B * CH;
        const int e1 = (e0 + CH < E) ? e0 + CH : E;
        int* rank = sh;                 // [0, SHW/2)
        int* base = sh + SHW / 2;       // [SHW/2, SHW)
        for (int b0 = 0; b0 < NB; b0 += SHW / 2) {
            int bw = (NB - b0 < SHW / 2) ? NB - b0 : SHW / 2;
            for (int i = t; i < bw; i += 256) {
                rank[i] = 0;
                base[i] = chist[(size_t)(b0 + i) * NC + B];
            }
            __syncthreads();
            for (int e = e0 + t; e < e1; e += 256) {
                int s, d;
                if (i32) { s = e32[e]; d = e32[(size_t)E + e]; }
                else     { s = (int)e64[e]; d = (int)e64[(size_t)E + e]; }
                int b = (d >> BSHIFT) - b0;
                if (b >= 0 && b < bw) {
                    int slot = base[b] + atomicAdd(&rank[b], 1);
                    bbuf[slot] = ((unsigned)(d & 127) << 25) | (unsigned)s;
                }
            }
            __syncthreads();
        }
    }
    grid.sync();

    // ---- phase F: per-bucket LDS counting sort -> esrc, rs, dinv ----
    if (B < NB) {
        int* hist = sh;          // 128
        int* off  = sh + 128;    // 128
        int* srcbuf = sh + 256;  // SCAP (3072)
        const int node0 = B << BSHIFT;
        const int nloc = (N - node0 < 128) ? N - node0 : 128;
        const int s0 = bbase[B], s1 = bbase[B + 1];
        const int cnt = s1 - s0;
        if (t < 128) hist[t] = 0;
        __syncthreads();
        for (int i = s0 + t; i < s1; i += 256)
            atomicAdd(&hist[bbuf[i] >> 25], 1);
        __syncthreads();
        if (t < 64) {   // wave 0: exclusive scan of 128 counts
            int carry = 0;
            #pragma unroll
            for (int base2 = 0; base2 < 128; base2 += 64) {
                int v = hist[base2 + t];
                int incl = v;
                #pragma unroll
                for (int o = 1; o < 64; o <<= 1) {
                    int nbr = __shfl_up(incl, o, 64);
                    if (t >= o) incl += nbr;
                }
                off[base2 + t] = carry + incl - v;
                carry += __shfl(incl, 63, 64);
            }
        }
        __syncthreads();
        if (t < nloc) {
            rs[node0 + t] = s0 + off[t];
            dinv[node0 + t] = rsqrtf((float)hist[t] + 1.0f);
        }
        __syncthreads();
        if (t < 128) hist[t] = 0;   // reuse as rank counters
        __syncthreads();
        if (cnt <= SCAP) {
            for (int i = s0 + t; i < s1; i += 256) {
                unsigned sd = bbuf[i];
                int lo = sd >> 25;
                int r = atomicAdd(&hist[lo], 1);
                srcbuf[off[lo] + r] = (int)(sd & 0x1ffffffu);
            }
            __syncthreads();
            for (int i = t; i < cnt; i += 256) esrc[s0 + i] = srcbuf[i];
        } else {        // fallback: scatter within bucket's global window
            for (int i = s0 + t; i < s1; i += 256) {
                unsigned sd = bbuf[i];
                int lo = sd >> 25;
                int r = atomicAdd(&hist[lo], 1);
                esrc[s0 + off[lo] + r] = (int)(sd & 0x1ffffffu);
            }
        }
    }
}

// ============================================================================
// Fallback (non-cooperative) CSR kernels — identical to the verified R1 path.
// ============================================================================
__global__ __launch_bounds__(256) void k_hist(const void* __restrict__ eidx, int E,
        int* __restrict__ chist, int NB, int NC,
        const float* __restrict__ W1, const float* __restrict__ W2,
        unsigned short* __restrict__ w1t, unsigned short* __restrict__ w2t,
        int K1, int M1, int K2, int M2) {
    __shared__ int hist[NBMAX];
    const int t = threadIdx.x, B = blockIdx.x;
    if (B < NC) {
        const int e0 = B * CH;
        const int e1 = (e0 + CH < E) ? e0 + CH : E;
        const bool i32 = detect_i32(eidx, E, t);
        const int* e32 = (const int*)eidx;
        const long long* e64 = (const long long*)eidx;
        for (int b0 = 0; b0 < NB; b0 += NBMAX) {
            int bw = (NB - b0 < NBMAX) ? NB - b0 : NBMAX;
            for (int i = t; i < bw; i += 256) hist[i] = 0;
            __syncthreads();
            for (int e = e0 + t; e < e1; e += 256) {
                int d = i32 ? e32[(size_t)E + e] : (int)e64[(size_t)E + e];
                int b = (d >> BSHIFT) - b0;
                if (b >= 0 && b < bw) atomicAdd(&hist[b], 1);
            }
            __syncthreads();
            for (int i = t; i < bw; i += 256) chist[(size_t)(b0 + i) * NC + B] = hist[i];
            __syncthreads();
        }
    } else if (B == NC) {
        for (int j = t; j < K1 * M1; j += 256) {
            int k = j / M1, n = j % M1;
            w1t[(size_t)n * K1 + k] = f2bf(W1[j]);
        }
    } else if (B == NC + 1) {
        for (int j = t; j < K2 * M2; j += 256) {
            int k = j / M2, n = j % M2;
            w2t[(size_t)n * K2 + k] = f2bf(W2[j]);
        }
    }
}

__global__ __launch_bounds__(256) void k_btot(const int* __restrict__ chist,
                                              int* __restrict__ btot, int NB, int NC) {
    int b = blockIdx.x * 4 + (threadIdx.x >> 6);
    if (b >= NB) return;
    int lane = threadIdx.x & 63;
    const int* row = chist + (size_t)b * NC;
    int v = 0;
    for (int i = lane; i < NC; i += 64) v += row[i];
    #pragma unroll
    for (int off = 32; off >= 1; off >>= 1) v += __shfl_xor(v, off, 64);
    if (lane == 0) btot[b] = v;
}

__global__ __launch_bounds__(1024) void k_bscan(const int* __restrict__ btot,
                                                int* __restrict__ bbase,
                                                int* __restrict__ rs_final,
                                                int NB, int N) {
    __shared__ int swt[16];
    const int t = threadIdx.x, lane = t & 63, w = t >> 6;
    int carry = 0;
    for (int base = 0; base < NB; base += 1024) {
        int i = base + t;
        int v = (i < NB) ? btot[i] : 0;
        int incl = v;
        #pragma unroll
        for (int off = 1; off < 64; off <<= 1) {
            int nbr = __shfl_up(incl, off, 64);
            if (lane >= off) incl += nbr;
        }
        if (lane == 63) swt[w] = incl;
        __syncthreads();
        int woff = 0;
        for (int j = 0; j < w; ++j) woff += swt[j];
        if (i < NB) bbase[i] = carry + woff + incl - v;
        int tot = 0;
        for (int j = 0; j < 16; ++j) tot += swt[j];
        carry += tot;
        __syncthreads();
    }
    if (t == 0) { bbase[NB] = carry; rs_final[N] = carry; }
}

__global__ __launch_bounds__(256) void k_hscan2(int* __restrict__ chist,
                                                const int* __restrict__ bbase,
                                                int NB, int NC) {
    int b = blockIdx.x * 4 + (threadIdx.x >> 6);
    if (b >= NB) return;
    int lane = threadIdx.x & 63;
    int* row = chist + (size_t)b * NC;
    int carry = bbase[b];
    for (int base = 0; base < NC; base += 64) {
        int i = base + lane;
        int v = (i < NC) ? row[i] : 0;
        int incl = v;
        #pragma unroll
        for (int off = 1; off < 64; off <<= 1) {
            int nbr = __shfl_up(incl, off, 64);
            if (lane >= off) incl += nbr;
        }
        if (i < NC) row[i] = carry + incl - v;
        carry += __shfl(incl, 63, 64);
    }
}

__global__ __launch_bounds__(256) void k_bfill(const void* __restrict__ eidx, int E,
                                               const int* __restrict__ chist,
                                               unsigned* __restrict__ bbuf, int NB, int NC) {
    __shared__ int rank[NBMAX];
    __shared__ int base[NBMAX];
    const int t = threadIdx.x, c = blockIdx.x;
    const int e0 = c * CH;
    const int e1 = (e0 + CH < E) ? e0 + CH : E;
    const bool i32 = detect_i32(eidx, E, t);
    const int* e32 = (const int*)eidx;
    const long long* e64 = (const long long*)eidx;
    for (int b0 = 0; b0 < NB; b0 += NBMAX) {
        int bw = (NB - b0 < NBMAX) ? NB - b0 : NBMAX;
        for (int i = t; i < bw; i += 256) {
            rank[i] = 0;
            base[i] = chist[(size_t)(b0 + i) * NC + c];
        }
        __syncthreads();
        for (int e = e0 + t; e < e1; e += 256) {
            int s, d;
            if (i32) { s = e32[e]; d = e32[(size_t)E + e]; }
            else     { s = (int)e64[e]; d = (int)e64[(size_t)E + e]; }
            int b = (d >> BSHIFT) - b0;
            if (b >= 0 && b < bw) {
                int slot = base[b] + atomicAdd(&rank[b], 1);
                bbuf[slot] = ((unsigned)(d & 127) << 25) | (unsigned)s;
            }
        }
        __syncthreads();
    }
}

__global__ __launch_bounds__(256) void k_sort(const unsigned* __restrict__ bbuf,
                                              const int* __restrict__ bbase,
                                              int* __restrict__ rs_final,
                                              float* __restrict__ dinv,
                                              int* __restrict__ esrc, int N) {
    __shared__ int hist[128];
    __shared__ int off[128];
    __shared__ int srcbuf[SCAP];
    const int b = blockIdx.x, t = threadIdx.x;
    const int node0 = b << BSHIFT;
    const int nloc = (N - node0 < 128) ? N - node0 : 128;
    const int s0 = bbase[b], s1 = bbase[b + 1];
    const int cnt = s1 - s0;
    if (t < 128) hist[t] = 0;
    __syncthreads();
    for (int i = s0 + t; i < s1; i += 256)
        atomicAdd(&hist[bbuf[i] >> 25], 1);
    __syncthreads();
    if (t < 64) {
        int carry = 0;
        #pragma unroll
        for (int base = 0; base < 128; base += 64) {
            int v = hist[base + t];
            int incl = v;
            #pragma unroll
            for (int o = 1; o < 64; o <<= 1) {
                int nbr = __shfl_up(incl, o, 64);
                if (t >= o) incl += nbr;
            }
            off[base + t] = carry + incl - v;
            carry += __shfl(incl, 63, 64);
        }
    }
    __syncthreads();
    if (t < nloc) {
        rs_final[node0 + t] = s0 + off[t];
        dinv[node0 + t] = rsqrtf((float)hist[t] + 1.0f);
    }
    __syncthreads();
    if (t < 128) hist[t] = 0;
    __syncthreads();
    if (cnt <= SCAP) {
        for (int i = s0 + t; i < s1; i += 256) {
            unsigned sd = bbuf[i];
            int lo = sd >> 25;
            int r = atomicAdd(&hist[lo], 1);
            srcbuf[off[lo] + r] = (int)(sd & 0x1ffffffu);
        }
        __syncthreads();
        for (int i = t; i < cnt; i += 256) esrc[s0 + i] = srcbuf[i];
    } else {
        for (int i = s0 + t; i < s1; i += 256) {
            unsigned sd = bbuf[i];
            int lo = sd >> 25;
            int r = atomicAdd(&hist[lo], 1);
            esrc[s0 + off[lo] + r] = (int)(sd & 0x1ffffffu);
        }
    }
}

// ============================================================================
// bf16 MFMA GEMM, tile 64 rows x BN cols (BN == M), K=128 one LDS stage.
// AF32: A is fp32, converted during staging. Epilogue folds dinv.
// ============================================================================
template<int BN, bool AF32>
__global__ __launch_bounds__(256, 3) void k_gemm(
        const void* __restrict__ Av, const unsigned short* __restrict__ Bt,
        const float* __restrict__ dinv, unsigned short* __restrict__ C,
        int N, int M) {
    constexpr int LD = 136;               // 128 + 8 u16 pad
    __shared__ unsigned short As[64 * LD];
    __shared__ unsigned short Bs[BN * LD];
    const int tid = threadIdx.x;
    const int wave = tid >> 6, lane = tid & 63;
    const int q = lane >> 4, tm = lane & 15;
    const int row0 = blockIdx.x * 64;

    {   // stage Bt rows [0,BN)
        const uint4* Bg = (const uint4*)Bt;
        #pragma unroll
        for (int it = 0; it < BN / 16; ++it) {
            int i = tid + it * 256;
            int r = i >> 4, o = i & 15;
            *(uint4*)&Bs[r * LD + o * 8] = Bg[(size_t)r * 16 + o];
        }
    }
    if (AF32) {   // stage A rows with inline fp32->bf16
        const float4* Ag = (const float4*)Av;
        #pragma unroll
        for (int it = 0; it < 8; ++it) {
            int i = tid + it * 256;
            int r = i >> 5, o = i & 31;
            int row = row0 + r;
            float4 v = make_float4(0.f, 0.f, 0.f, 0.f);
            if (row < N) v = Ag[(size_t)row * 32 + o];
            uint2 pk;
            pk.x = pack_bf16(v.x, v.y);
            pk.y = pack_bf16(v.z, v.w);
            *(uint2*)&As[r * LD + o * 4] = pk;
        }
    } else {      // stage bf16 A rows
        const uint4* Ag = (const uint4*)Av;
        #pragma unroll
        for (int it = 0; it < 4; ++it) {
            int i = tid + it * 256;
            int r = i >> 4, o = i & 15;
            int row = row0 + r;
            uint4 v = make_uint4(0, 0, 0, 0);
            if (row < N) v = Ag[(size_t)row * 16 + o];
            *(uint4*)&As[r * LD + o * 8] = v;
        }
    }
    __syncthreads();

    constexpr int NG = BN / 16;
    floatx4 acc[NG];
    #pragma unroll
    for (int g = 0; g < NG; ++g) acc[g] = (floatx4){0.f, 0.f, 0.f, 0.f};

    const int arow = wave * 16 + tm;
    #pragma unroll
    for (int kc = 0; kc < 4; ++kc) {
        short8 af = *(const short8*)&As[arow * LD + kc * 32 + q * 8];
        #pragma unroll
        for (int g = 0; g < NG; ++g) {
            short8 bf = *(const short8*)&Bs[(g * 16 + tm) * LD + kc * 32 + q * 8];
            acc[g] = __builtin_amdgcn_mfma_f32_16x16x32_bf16(af, bf, acc[g], 0, 0, 0);
        }
    }

    float dv[4];
    #pragma unroll
    for (int r = 0; r < 4; ++r) {
        int row = row0 + wave * 16 + q * 4 + r;
        dv[r] = (row < N) ? dinv[row] : 0.f;
    }
    #pragma unroll
    for (int g = 0; g < NG; ++g) {
        #pragma unroll
        for (int r = 0; r < 4; ++r) {
            int row = row0 + wave * 16 + q * 4 + r;
            if (row < N) C[(size_t)row * M + g * 16 + tm] = f2bf(dv[r] * acc[g][r]);
        }
    }
}

// ---- aggregation, F=128: half-wave per edge, dwordx2 gathers ----
__global__ __launch_bounds__(256) void k_agg128(const unsigned* __restrict__ Hb,
        const float* __restrict__ dinv, const int* __restrict__ rs,
        const int* __restrict__ esrc, const float* __restrict__ bias,
        uint2* __restrict__ out, int N) {
    int wid = (blockIdx.x * 256 + threadIdx.x) >> 6;
    if (wid >= N) return;
    int l = threadIdx.x & 63;
    int hi = l >> 5;
    int q  = l & 31;
    const uint2* H2 = (const uint2*)Hb;      // row stride = 32 uint2
    float di = dinv[wid];
    float a0 = 0.f, a1 = 0.f, a2 = 0.f, a3 = 0.f;
    int k = rs[wid], kend = rs[wid + 1];
    for (; k + 8 <= kend; k += 8) {
        int s[4];
        #pragma unroll
        for (int j = 0; j < 4; ++j) s[j] = esrc[k + 2 * j + hi];
        uint2 g[4];
        #pragma unroll
        for (int j = 0; j < 4; ++j) g[j] = H2[(size_t)s[j] * 32 + q];
        #pragma unroll
        for (int j = 0; j < 4; ++j) {
            a0 += bf_lo(g[j].x); a1 += bf_hi(g[j].x);
            a2 += bf_lo(g[j].y); a3 += bf_hi(g[j].y);
        }
    }
    if (k + 4 <= kend) {
        int s[2];
        #pragma unroll
        for (int j = 0; j < 2; ++j) s[j] = esrc[k + 2 * j + hi];
        uint2 g[2];
        #pragma unroll
        for (int j = 0; j < 2; ++j) g[j] = H2[(size_t)s[j] * 32 + q];
        #pragma unroll
        for (int j = 0; j < 2; ++j) {
            a0 += bf_lo(g[j].x); a1 += bf_hi(g[j].x);
            a2 += bf_lo(g[j].y); a3 += bf_hi(g[j].y);
        }
        k += 4;
    }
    if (k + 2 <= kend) {
        int s = esrc[k + hi];
        uint2 g = H2[(size_t)s * 32 + q];
        a0 += bf_lo(g.x); a1 += bf_hi(g.x);
        a2 += bf_lo(g.y); a3 += bf_hi(g.y);
        k += 2;
    }
    if (k < kend && hi == 0) {
        int s = esrc[k];
        uint2 g = H2[(size_t)s * 32 + q];
        a0 += bf_lo(g.x); a1 += bf_hi(g.x);
        a2 += bf_lo(g.y); a3 += bf_hi(g.y);
    }
    a0 += __shfl_xor(a0, 32, 64);
    a1 += __shfl_xor(a1, 32, 64);
    a2 += __shfl_xor(a2, 32, 64);
    a3 += __shfl_xor(a3, 32, 64);
    uint2 sr = H2[(size_t)wid * 32 + q];     // self row (already dinv-scaled)
    a0 += bf_lo(sr.x); a1 += bf_hi(sr.x);
    a2 += bf_lo(sr.y); a3 += bf_hi(sr.y);
    float4 b = ((const float4*)bias)[q];
    float o0 = fmaxf(fmaf(di, a0, b.x), 0.f);   // layer 1: ReLU
    float o1 = fmaxf(fmaf(di, a1, b.y), 0.f);
    float o2 = fmaxf(fmaf(di, a2, b.z), 0.f);
    float o3 = fmaxf(fmaf(di, a3, b.w), 0.f);
    if (hi == 0) {
        uint2 pk;
        pk.x = pack_bf16(o0, o1);
        pk.y = pack_bf16(o2, o3);
        out[(size_t)wid * 32 + q] = pk;
    }
}

// ---- aggregation, F=64: half-wave per edge, dword gathers ----
__global__ __launch_bounds__(256) void k_agg64(const unsigned short* __restrict__ Hb,
        const float* __restrict__ dinv, const int* __restrict__ rs,
        const int* __restrict__ esrc, const float* __restrict__ bias,
        float2* __restrict__ out, int N) {
    int wid = (blockIdx.x * 256 + threadIdx.x) >> 6;
    if (wid >= N) return;
    int l = threadIdx.x & 63;
    int hi = l >> 5;
    int q  = l & 31;
    const unsigned* H1 = (const unsigned*)Hb;    // row stride = 32 dwords
    float di = dinv[wid];
    float a0 = 0.f, a1 = 0.f;
    int k = rs[wid], kend = rs[wid + 1];
    for (; k + 8 <= kend; k += 8) {
        int s[4];
        #pragma unroll
        for (int j = 0; j < 4; ++j) s[j] = esrc[k + 2 * j + hi];
        unsigned g[4];
        #pragma unroll
        for (int j = 0; j < 4; ++j) g[j] = H1[(size_t)s[j] * 32 + q];
        #pragma unroll
        for (int j = 0; j < 4; ++j) { a0 += bf_lo(g[j]); a1 += bf_hi(g[j]); }
    }
    if (k + 4 <= kend) {
        int s[2];
        #pragma unroll
        for (int j = 0; j < 2; ++j) s[j] = esrc[k + 2 * j + hi];
        unsigned g[2];
        #pragma unroll
        for (int j = 0; j < 2; ++j) g[j] = H1[(size_t)s[j] * 32 + q];
        #pragma unroll
        for (int j = 0; j < 2; ++j) { a0 += bf_lo(g[j]); a1 += bf_hi(g[j]); }
        k += 4;
    }
    if (k + 2 <= kend) {
        int s = esrc[k + hi];
        unsigned g = H1[(size_t)s * 32 + q];
        a0 += bf_lo(g); a1 += bf_hi(g);
        k += 2;
    }
    if (k < kend && hi == 0) {
        unsigned g = H1[(size_t)esrc[k] * 32 + q];
        a0 += bf_lo(g); a1 += bf_hi(g);
    }
    a0 += __shfl_xor(a0, 32, 64);
    a1 += __shfl_xor(a1, 32, 64);
    unsigned sr = H1[(size_t)wid * 32 + q];
    a0 += bf_lo(sr); a1 += bf_hi(sr);
    float2 b = ((const float2*)bias)[q];
    if (hi == 0) {
        float2 o;
        o.x = fmaf(di, a0, b.x);
        o.y = fmaf(di, a1, b.y);
        out[(size_t)wid * 32 + q] = o;
    }
}

extern "C" void kernel_launch(void* const* d_in, const int* in_sizes, int n_in,
                              void* d_out, int out_size, void* d_ws, size_t ws_size,
                              hipStream_t stream) {
    const void*  ei = d_in[1];
    const float* x  = (const float*)d_in[0];
    const float* W1 = (const float*)d_in[2];
    const float* b1 = (const float*)d_in[3];
    const float* W2 = (const float*)d_in[4];
    const float* b2 = (const float*)d_in[5];

    int HID = in_sizes[3];            // 128
    int IN  = in_sizes[2] / HID;      // 128
    int OUT = in_sizes[4] / HID;      // 64
    int N   = in_sizes[0] / IN;       // 50000
    int E   = in_sizes[1] / 2;        // 800000
    int NB  = (N + 127) >> BSHIFT;    // dst buckets (391)
    int NC  = (E + CH - 1) / CH;      // chunks (391)

    char* p = (char*)d_ws;
    int* chist     = (int*)p;   p += align256((size_t)NB * NC * 4);
    int* btot      = (int*)p;   p += align256((size_t)NB * 4);
    int* bbase     = (int*)p;   p += align256((size_t)(NB + 1) * 4);
    int* rs_final  = (int*)p;   p += align256((size_t)(N + 1) * 4);
    int* esrc      = (int*)p;   p += align256((size_t)E * 4);
    float* dinv    = (float*)p; p += align256((size_t)N * 4);
    unsigned short* w1t = (unsigned short*)p; p += align256((size_t)HID * IN * 2);
    unsigned short* w2t = (unsigned short*)p; p += align256((size_t)OUT * HID * 2);
    // bbuf (E uint, dead after sort phase) overlays hb (N*HID bf16, written later)
    size_t hb_bytes = (size_t)N * HID * 2, bbuf_bytes = (size_t)E * 4;
    unsigned* bbuf = (unsigned*)p;
    unsigned short* hb = (unsigned short*)p;
    p += align256(hb_bytes > bbuf_bytes ? hb_bytes : bbuf_bytes);
    unsigned short* h1b = (unsigned short*)p; p += align256((size_t)N * HID * 2);
    unsigned short* h2b = (unsigned short*)p; p += align256((size_t)N * OUT * 2);

    // ---- CSR build: single cooperative dispatch (6 kernels fused) ----
    int G = NB > NC ? NB : NC;
    int K1v = IN, M1v = HID, K2v = HID, M2v = OUT;
    void* args[] = { (void*)&ei, &E, &N, &NB, &NC,
                     (void*)&chist, (void*)&btot, (void*)&bbase,
                     (void*)&rs_final, (void*)&dinv, (void*)&bbuf, (void*)&esrc,
                     (void*)&W1, (void*)&W2, (void*)&w1t, (void*)&w2t,
                     &K1v, &M1v, &K2v, &M2v };
    hipError_t cerr = hipLaunchCooperativeKernel((const void*)k_csr,
                                                 dim3(G), dim3(256), args, 0, stream);
    if (cerr != hipSuccess) {
        // fallback: verified 6-dispatch path
        k_hist<<<NC + 2, 256, 0, stream>>>(ei, E, chist, NB, NC,
                                           W1, W2, w1t, w2t, IN, HID, HID, OUT);
        k_btot<<<(NB + 3) / 4, 256, 0, stream>>>(chist, btot, NB, NC);
        k_bscan<<<1, 1024, 0, stream>>>(btot, bbase, rs_final, NB, N);
        k_hscan2<<<(NB + 3) / 4, 256, 0, stream>>>(chist, bbase, NB, NC);
        k_bfill<<<NC, 256, 0, stream>>>(ei, E, chist, bbuf, NB, NC);
        k_sort<<<NB, 256, 0, stream>>>(bbuf, bbase, rs_final, dinv, esrc, N);
    }

    // layer 1: hb = bf16(dinv * (x @ W1)) ; h1b = bf16(relu(dinv*sum + b1))
    k_gemm<128, true><<<(N + 63) / 64, 256, 0, stream>>>(x, w1t, dinv, hb, N, HID);
    k_agg128<<<(N + 3) / 4, 256, 0, stream>>>((unsigned*)hb, dinv, rs_final, esrc, b1,
                                              (uint2*)h1b, N);

    // layer 2: h2b = bf16(dinv * (h1b @ W2)) ; out = dinv*sum + b2
    k_gemm<64, false><<<(N + 63) / 64, 256, 0, stream>>>(h1b, w2t, dinv, h2b, N, OUT);
    k_agg64<<<(N + 3) / 4, 256, 0, stream>>>(h2b, dinv, rs_final, esrc, b2,
                                             (float2*)d_out, N);
}

// Round 4
// 201.397 us; speedup vs baseline: 2.2220x; 2.2220x over previous
//
#include <hip/hip_runtime.h>
#include <stdint.h>

typedef __attribute__((ext_vector_type(8))) short short8;
typedef __attribute__((ext_vector_type(4))) float floatx4;

static inline size_t align256(size_t x) { return (x + 255) & ~size_t(255); }

__device__ __forceinline__ unsigned short f2bf(float f) {
    unsigned u = __float_as_uint(f);
    u += 0x7fff + ((u >> 16) & 1);     // round-to-nearest-even
    return (unsigned short)(u >> 16);
}
__device__ __forceinline__ unsigned pack_bf16(float a, float b) {
    return (unsigned)f2bf(a) | ((unsigned)f2bf(b) << 16);
}
__device__ __forceinline__ float bf_lo(unsigned u) { return __uint_as_float(u << 16); }
__device__ __forceinline__ float bf_hi(unsigned u) { return __uint_as_float(u & 0xffff0000u); }

#define BSHIFT 7     // 128 nodes per dst-bucket
#define NBMAX 1024   // max buckets per LDS window
#define CH 2048      // edges per chunk
#define SCAP 3072    // LDS-staged pairs per bucket
// bbuf packing: (dst&127)<<25 | src  -- requires N < 2^25 (here N=50000)

// per-block edge dtype self-detection: int32 data read as int64 pairs gives
// out-of-range values with prob ~1 per sample; 256 samples => certain.
__device__ __forceinline__ bool detect_i32(const void* eidx, int E, int t) {
    const long long* e64 = (const long long*)eidx;
    int nchk = E < 256 ? E : 256;
    long long v = e64[t % nchk];
    int bad = (v < 0 || v > 0x7fffffffLL) ? 1 : 0;
    return __syncthreads_or(bad) != 0;
}

// ---- chunk x bucket histogram (LDS only); blocks NC/NC+1 convert W1/W2 ----
__global__ __launch_bounds__(256) void k_hist(const void* __restrict__ eidx, int E,
        int* __restrict__ chist, int NB, int NC,
        const float* __restrict__ W1, const float* __restrict__ W2,
        unsigned short* __restrict__ w1t, unsigned short* __restrict__ w2t,
        int K1, int M1, int K2, int M2) {
    __shared__ int hist[NBMAX];
    const int t = threadIdx.x, B = blockIdx.x;
    if (B < NC) {
        const int e0 = B * CH;
        const int e1 = (e0 + CH < E) ? e0 + CH : E;
        const bool i32 = detect_i32(eidx, E, t);
        const int* e32 = (const int*)eidx;
        const long long* e64 = (const long long*)eidx;
        for (int b0 = 0; b0 < NB; b0 += NBMAX) {
            int bw = (NB - b0 < NBMAX) ? NB - b0 : NBMAX;
            for (int i = t; i < bw; i += 256) hist[i] = 0;
            __syncthreads();
            for (int e = e0 + t; e < e1; e += 256) {
                int d = i32 ? e32[(size_t)E + e] : (int)e64[(size_t)E + e];
                int b = (d >> BSHIFT) - b0;
                if (b >= 0 && b < bw) atomicAdd(&hist[b], 1);
            }
            __syncthreads();
            for (int i = t; i < bw; i += 256) chist[(size_t)(b0 + i) * NC + B] = hist[i];
            __syncthreads();
        }
    } else if (B == NC) {
        for (int j = t; j < K1 * M1; j += 256) {
            int k = j / M1, n = j % M1;
            w1t[(size_t)n * K1 + k] = f2bf(W1[j]);
        }
    } else if (B == NC + 1) {
        for (int j = t; j < K2 * M2; j += 256) {
            int k = j / M2, n = j % M2;
            w2t[(size_t)n * K2 + k] = f2bf(W2[j]);
        }
    }
}

// ---- bucket totals: one wave per bucket sums its chist row ----
__global__ __launch_bounds__(256) void k_btot(const int* __restrict__ chist,
                                              int* __restrict__ btot, int NB, int NC) {
    int b = blockIdx.x * 4 + (threadIdx.x >> 6);
    if (b >= NB) return;
    int lane = threadIdx.x & 63;
    const int* row = chist + (size_t)b * NC;
    int v = 0;
    for (int i = lane; i < NC; i += 64) v += row[i];
    #pragma unroll
    for (int off = 32; off >= 1; off >>= 1) v += __shfl_xor(v, off, 64);
    if (lane == 0) btot[b] = v;
}

// ---- single-block exclusive scan of bucket totals -> bbase[NB+1]; rs_final[N]=E ----
__global__ __launch_bounds__(1024) void k_bscan(const int* __restrict__ btot,
                                                int* __restrict__ bbase,
                                                int* __restrict__ rs_final,
                                                int NB, int N) {
    __shared__ int swt[16];
    const int t = threadIdx.x, lane = t & 63, w = t >> 6;
    int carry = 0;
    for (int base = 0; base < NB; base += 1024) {
        int i = base + t;
        int v = (i < NB) ? btot[i] : 0;
        int incl = v;
        #pragma unroll
        for (int off = 1; off < 64; off <<= 1) {
            int nbr = __shfl_up(incl, off, 64);
            if (lane >= off) incl += nbr;
        }
        if (lane == 63) swt[w] = incl;
        __syncthreads();
        int woff = 0;
        for (int j = 0; j < w; ++j) woff += swt[j];
        if (i < NB) bbase[i] = carry + woff + incl - v;
        int tot = 0;
        for (int j = 0; j < 16; ++j) tot += swt[j];
        carry += tot;
        __syncthreads();
    }
    if (t == 0) { bbase[NB] = carry; rs_final[N] = carry; }
}

// ---- per-bucket chunk scan seeded with bbase: chist[b][c] -> global slot base ----
__global__ __launch_bounds__(256) void k_hscan2(int* __restrict__ chist,
                                                const int* __restrict__ bbase,
                                                int NB, int NC) {
    int b = blockIdx.x * 4 + (threadIdx.x >> 6);
    if (b >= NB) return;
    int lane = threadIdx.x & 63;
    int* row = chist + (size_t)b * NC;
    int carry = bbase[b];
    for (int base = 0; base < NC; base += 64) {
        int i = base + lane;
        int v = (i < NC) ? row[i] : 0;
        int incl = v;
        #pragma unroll
        for (int off = 1; off < 64; off <<= 1) {
            int nbr = __shfl_up(incl, off, 64);
            if (lane >= off) incl += nbr;
        }
        if (i < NC) row[i] = carry + incl - v;
        carry += __shfl(incl, 63, 64);
    }
}

// ---- binned fill: deterministic base + LDS rank; packed uint payload ----
__global__ __launch_bounds__(256) void k_bfill(const void* __restrict__ eidx, int E,
                                               const int* __restrict__ chist,
                                               unsigned* __restrict__ bbuf, int NB, int NC) {
    __shared__ int rank[NBMAX];
    __shared__ int base[NBMAX];
    const int t = threadIdx.x, c = blockIdx.x;
    const int e0 = c * CH;
    const int e1 = (e0 + CH < E) ? e0 + CH : E;
    const bool i32 = detect_i32(eidx, E, t);
    const int* e32 = (const int*)eidx;
    const long long* e64 = (const long long*)eidx;
    for (int b0 = 0; b0 < NB; b0 += NBMAX) {
        int bw = (NB - b0 < NBMAX) ? NB - b0 : NBMAX;
        for (int i = t; i < bw; i += 256) {
            rank[i] = 0;
            base[i] = chist[(size_t)(b0 + i) * NC + c];
        }
        __syncthreads();
        for (int e = e0 + t; e < e1; e += 256) {
            int s, d;
            if (i32) { s = e32[e]; d = e32[(size_t)E + e]; }
            else     { s = (int)e64[e]; d = (int)e64[(size_t)E + e]; }
            int b = (d >> BSHIFT) - b0;
            if (b >= 0 && b < bw) {
                int slot = base[b] + atomicAdd(&rank[b], 1);
                bbuf[slot] = ((unsigned)(d & 127) << 25) | (unsigned)s;
            }
        }
        __syncthreads();
    }
}

// ---- per-bucket LDS counting sort: emits esrc (coalesced), rs_final, dinv ----
__global__ __launch_bounds__(256) void k_sort(const unsigned* __restrict__ bbuf,
                                              const int* __restrict__ bbase,
                                              int* __restrict__ rs_final,
                                              float* __restrict__ dinv,
                                              int* __restrict__ esrc, int N) {
    __shared__ int hist[128];
    __shared__ int off[128];
    __shared__ int srcbuf[SCAP];
    const int b = blockIdx.x, t = threadIdx.x;
    const int node0 = b << BSHIFT;
    const int nloc = (N - node0 < 128) ? N - node0 : 128;
    const int s0 = bbase[b], s1 = bbase[b + 1];
    const int cnt = s1 - s0;
    if (t < 128) hist[t] = 0;
    __syncthreads();
    for (int i = s0 + t; i < s1; i += 256)
        atomicAdd(&hist[bbuf[i] >> 25], 1);
    __syncthreads();
    if (t < 64) {   // wave 0: exclusive scan of 128 counts
        int carry = 0;
        #pragma unroll
        for (int base = 0; base < 128; base += 64) {
            int v = hist[base + t];
            int incl = v;
            #pragma unroll
            for (int o = 1; o < 64; o <<= 1) {
                int nbr = __shfl_up(incl, o, 64);
                if (t >= o) incl += nbr;
            }
            off[base + t] = carry + incl - v;
            carry += __shfl(incl, 63, 64);
        }
    }
    __syncthreads();
    if (t < nloc) {
        rs_final[node0 + t] = s0 + off[t];
        dinv[node0 + t] = rsqrtf((float)hist[t] + 1.0f);
    }
    __syncthreads();
    if (t < 128) hist[t] = 0;   // reuse as rank counters
    __syncthreads();
    if (cnt <= SCAP) {
        for (int i = s0 + t; i < s1; i += 256) {
            unsigned sd = bbuf[i];
            int lo = sd >> 25;
            int r = atomicAdd(&hist[lo], 1);
            srcbuf[off[lo] + r] = (int)(sd & 0x1ffffffu);
        }
        __syncthreads();
        for (int i = t; i < cnt; i += 256) esrc[s0 + i] = srcbuf[i];
    } else {        // fallback: scatter within bucket's global window
        for (int i = s0 + t; i < s1; i += 256) {
            unsigned sd = bbuf[i];
            int lo = sd >> 25;
            int r = atomicAdd(&hist[lo], 1);
            esrc[s0 + off[lo] + r] = (int)(sd & 0x1ffffffu);
        }
    }
}

// ============================================================================
// bf16 MFMA GEMM, tile 64 rows x BN cols (BN == M), K=128 one LDS stage.
// AF32: A is fp32, converted during staging. Epilogue folds dinv.
// ============================================================================
template<int BN, bool AF32>
__global__ __launch_bounds__(256, 3) void k_gemm(
        const void* __restrict__ Av, const unsigned short* __restrict__ Bt,
        const float* __restrict__ dinv, unsigned short* __restrict__ C,
        int N, int M) {
    constexpr int LD = 136;               // 128 + 8 u16 pad
    __shared__ unsigned short As[64 * LD];
    __shared__ unsigned short Bs[BN * LD];
    const int tid = threadIdx.x;
    const int wave = tid >> 6, lane = tid & 63;
    const int q = lane >> 4, tm = lane & 15;
    const int row0 = blockIdx.x * 64;

    {   // stage Bt rows [0,BN)
        const uint4* Bg = (const uint4*)Bt;
        #pragma unroll
        for (int it = 0; it < BN / 16; ++it) {
            int i = tid + it * 256;
            int r = i >> 4, o = i & 15;
            *(uint4*)&Bs[r * LD + o * 8] = Bg[(size_t)r * 16 + o];
        }
    }
    if (AF32) {   // stage A rows with inline fp32->bf16
        const float4* Ag = (const float4*)Av;
        #pragma unroll
        for (int it = 0; it < 8; ++it) {
            int i = tid + it * 256;
            int r = i >> 5, o = i & 31;
            int row = row0 + r;
            float4 v = make_float4(0.f, 0.f, 0.f, 0.f);
            if (row < N) v = Ag[(size_t)row * 32 + o];
            uint2 pk;
            pk.x = pack_bf16(v.x, v.y);
            pk.y = pack_bf16(v.z, v.w);
            *(uint2*)&As[r * LD + o * 4] = pk;
        }
    } else {      // stage bf16 A rows
        const uint4* Ag = (const uint4*)Av;
        #pragma unroll
        for (int it = 0; it < 4; ++it) {
            int i = tid + it * 256;
            int r = i >> 4, o = i & 15;
            int row = row0 + r;
            uint4 v = make_uint4(0, 0, 0, 0);
            if (row < N) v = Ag[(size_t)row * 16 + o];
            *(uint4*)&As[r * LD + o * 8] = v;
        }
    }
    __syncthreads();

    constexpr int NG = BN / 16;
    floatx4 acc[NG];
    #pragma unroll
    for (int g = 0; g < NG; ++g) acc[g] = (floatx4){0.f, 0.f, 0.f, 0.f};

    const int arow = wave * 16 + tm;
    #pragma unroll
    for (int kc = 0; kc < 4; ++kc) {
        short8 af = *(const short8*)&As[arow * LD + kc * 32 + q * 8];
        #pragma unroll
        for (int g = 0; g < NG; ++g) {
            short8 bf = *(const short8*)&Bs[(g * 16 + tm) * LD + kc * 32 + q * 8];
            acc[g] = __builtin_amdgcn_mfma_f32_16x16x32_bf16(af, bf, acc[g], 0, 0, 0);
        }
    }

    float dv[4];
    #pragma unroll
    for (int r = 0; r < 4; ++r) {
        int row = row0 + wave * 16 + q * 4 + r;
        dv[r] = (row < N) ? dinv[row] : 0.f;
    }
    #pragma unroll
    for (int g = 0; g < NG; ++g) {
        #pragma unroll
        for (int r = 0; r < 4; ++r) {
            int row = row0 + wave * 16 + q * 4 + r;
            if (row < N) C[(size_t)row * M + g * 16 + tm] = f2bf(dv[r] * acc[g][r]);
        }
    }
}

#define ACC8(v) do { \
    a0 += bf_lo((v).x); a1 += bf_hi((v).x); \
    a2 += bf_lo((v).y); a3 += bf_hi((v).y); \
    a4 += bf_lo((v).z); a5 += bf_hi((v).z); \
    a6 += bf_lo((v).w); a7 += bf_hi((v).w); } while (0)

// ---- aggregation, F=128: full wave, 4 rows per dwordx4 gather ----
// One coalesced 64-wide index load per 64 edges; indices broadcast via shfl
// (no per-edge vmem index loads). Lane group g=l>>4 takes edge slot g of 4;
// lane q=l&15 covers 16B (8 bf16 feats). Butterfly-merge 4 partial sums.
__global__ __launch_bounds__(256) void k_agg128(const uint4* __restrict__ H4,
        const float* __restrict__ dinv, const int* __restrict__ rs,
        const int* __restrict__ esrc, const float* __restrict__ bias,
        uint4* __restrict__ out, int N) {
    int wid = (blockIdx.x * 256 + threadIdx.x) >> 6;
    if (wid >= N) return;
    int l = threadIdx.x & 63;
    int g = l >> 4;            // edge slot within group-of-4
    int q = l & 15;            // uint4 index within 256B row
    float a0 = 0.f, a1 = 0.f, a2 = 0.f, a3 = 0.f;
    float a4 = 0.f, a5 = 0.f, a6 = 0.f, a7 = 0.f;
    int k0 = rs[wid], kend = rs[wid + 1];
    for (int base = k0; base < kend; base += 64) {
        int rem = kend - base; if (rem > 64) rem = 64;
        int idx = esrc[base + (l < rem ? l : 0)];    // coalesced, clamped
        int e0 = 0;
        for (; e0 + 16 <= rem; e0 += 16) {           // 4 gathers in flight
            int s0 = __shfl(idx, e0 + g, 64);
            int s1 = __shfl(idx, e0 + 4 + g, 64);
            int s2 = __shfl(idx, e0 + 8 + g, 64);
            int s3 = __shfl(idx, e0 + 12 + g, 64);
            uint4 v0 = H4[(size_t)s0 * 16 + q];
            uint4 v1 = H4[(size_t)s1 * 16 + q];
            uint4 v2 = H4[(size_t)s2 * 16 + q];
            uint4 v3 = H4[(size_t)s3 * 16 + q];
            ACC8(v0); ACC8(v1); ACC8(v2); ACC8(v3);
        }
        for (; e0 + 4 <= rem; e0 += 4) {
            int s0 = __shfl(idx, e0 + g, 64);
            uint4 v0 = H4[(size_t)s0 * 16 + q];
            ACC8(v0);
        }
        if (e0 < rem) {                              // ragged 1..3 edges
            int s0 = __shfl(idx, e0 + g, 64);
            if (e0 + g < rem) {
                uint4 v0 = H4[(size_t)s0 * 16 + q];
                ACC8(v0);
            }
        }
    }
    // merge the 4 edge-slot partials (lanes differing in bits 4,5)
    a0 += __shfl_xor(a0, 16, 64); a1 += __shfl_xor(a1, 16, 64);
    a2 += __shfl_xor(a2, 16, 64); a3 += __shfl_xor(a3, 16, 64);
    a4 += __shfl_xor(a4, 16, 64); a5 += __shfl_xor(a5, 16, 64);
    a6 += __shfl_xor(a6, 16, 64); a7 += __shfl_xor(a7, 16, 64);
    a0 += __shfl_xor(a0, 32, 64); a1 += __shfl_xor(a1, 32, 64);
    a2 += __shfl_xor(a2, 32, 64); a3 += __shfl_xor(a3, 32, 64);
    a4 += __shfl_xor(a4, 32, 64); a5 += __shfl_xor(a5, 32, 64);
    a6 += __shfl_xor(a6, 32, 64); a7 += __shfl_xor(a7, 32, 64);
    if (g == 0) {
        uint4 sv = H4[(size_t)wid * 16 + q];         // self row (dinv-scaled)
        ACC8(sv);
        float di = dinv[wid];
        float4 bA = ((const float4*)bias)[q * 2];
        float4 bB = ((const float4*)bias)[q * 2 + 1];
        float o0 = fmaxf(fmaf(di, a0, bA.x), 0.f);   // layer 1: ReLU
        float o1 = fmaxf(fmaf(di, a1, bA.y), 0.f);
        float o2 = fmaxf(fmaf(di, a2, bA.z), 0.f);
        float o3 = fmaxf(fmaf(di, a3, bA.w), 0.f);
        float o4 = fmaxf(fmaf(di, a4, bB.x), 0.f);
        float o5 = fmaxf(fmaf(di, a5, bB.y), 0.f);
        float o6 = fmaxf(fmaf(di, a6, bB.z), 0.f);
        float o7 = fmaxf(fmaf(di, a7, bB.w), 0.f);
        uint4 pk;
        pk.x = pack_bf16(o0, o1);
        pk.y = pack_bf16(o2, o3);
        pk.z = pack_bf16(o4, o5);
        pk.w = pack_bf16(o6, o7);
        out[(size_t)wid * 16 + q] = pk;
    }
}

// ---- aggregation, F=64: full wave, 8 rows per dwordx4 gather ----
__global__ __launch_bounds__(256) void k_agg64(const uint4* __restrict__ H4,
        const float* __restrict__ dinv, const int* __restrict__ rs,
        const int* __restrict__ esrc, const float* __restrict__ bias,
        float4* __restrict__ out, int N) {
    int wid = (blockIdx.x * 256 + threadIdx.x) >> 6;
    if (wid >= N) return;
    int l = threadIdx.x & 63;
    int g = l >> 3;            // edge slot within group-of-8
    int q = l & 7;             // uint4 index within 128B row
    float a0 = 0.f, a1 = 0.f, a2 = 0.f, a3 = 0.f;
    float a4 = 0.f, a5 = 0.f, a6 = 0.f, a7 = 0.f;
    int k0 = rs[wid], kend = rs[wid + 1];
    for (int base = k0; base < kend; base += 64) {
        int rem = kend - base; if (rem > 64) rem = 64;
        int idx = esrc[base + (l < rem ? l : 0)];    // coalesced, clamped
        int e0 = 0;
        for (; e0 + 32 <= rem; e0 += 32) {           // 4 gathers in flight
            int s0 = __shfl(idx, e0 + g, 64);
            int s1 = __shfl(idx, e0 + 8 + g, 64);
            int s2 = __shfl(idx, e0 + 16 + g, 64);
            int s3 = __shfl(idx, e0 + 24 + g, 64);
            uint4 v0 = H4[(size_t)s0 * 8 + q];
            uint4 v1 = H4[(size_t)s1 * 8 + q];
            uint4 v2 = H4[(size_t)s2 * 8 + q];
            uint4 v3 = H4[(size_t)s3 * 8 + q];
            ACC8(v0); ACC8(v1); ACC8(v2); ACC8(v3);
        }
        for (; e0 + 8 <= rem; e0 += 8) {
            int s0 = __shfl(idx, e0 + g, 64);
            uint4 v0 = H4[(size_t)s0 * 8 + q];
            ACC8(v0);
        }
        if (e0 < rem) {                              // ragged 1..7 edges
            int s0 = __shfl(idx, e0 + g, 64);
            if (e0 + g < rem) {
                uint4 v0 = H4[(size_t)s0 * 8 + q];
                ACC8(v0);
            }
        }
    }
    // merge the 8 edge-slot partials (lanes differing in bits 3,4,5)
    a0 += __shfl_xor(a0, 8, 64);  a1 += __shfl_xor(a1, 8, 64);
    a2 += __shfl_xor(a2, 8, 64);  a3 += __shfl_xor(a3, 8, 64);
    a4 += __shfl_xor(a4, 8, 64);  a5 += __shfl_xor(a5, 8, 64);
    a6 += __shfl_xor(a6, 8, 64);  a7 += __shfl_xor(a7, 8, 64);
    a0 += __shfl_xor(a0, 16, 64); a1 += __shfl_xor(a1, 16, 64);
    a2 += __shfl_xor(a2, 16, 64); a3 += __shfl_xor(a3, 16, 64);
    a4 += __shfl_xor(a4, 16, 64); a5 += __shfl_xor(a5, 16, 64);
    a6 += __shfl_xor(a6, 16, 64); a7 += __shfl_xor(a7, 16, 64);
    a0 += __shfl_xor(a0, 32, 64); a1 += __shfl_xor(a1, 32, 64);
    a2 += __shfl_xor(a2, 32, 64); a3 += __shfl_xor(a3, 32, 64);
    a4 += __shfl_xor(a4, 32, 64); a5 += __shfl_xor(a5, 32, 64);
    a6 += __shfl_xor(a6, 32, 64); a7 += __shfl_xor(a7, 32, 64);
    if (g == 0) {
        uint4 sv = H4[(size_t)wid * 8 + q];          // self row (dinv-scaled)
        ACC8(sv);
        float di = dinv[wid];
        float4 bA = ((const float4*)bias)[q * 2];
        float4 bB = ((const float4*)bias)[q * 2 + 1];
        float4 oA, oB;
        oA.x = fmaf(di, a0, bA.x);
        oA.y = fmaf(di, a1, bA.y);
        oA.z = fmaf(di, a2, bA.z);
        oA.w = fmaf(di, a3, bA.w);
        oB.x = fmaf(di, a4, bB.x);
        oB.y = fmaf(di, a5, bB.y);
        oB.z = fmaf(di, a6, bB.z);
        oB.w = fmaf(di, a7, bB.w);
        out[(size_t)wid * 16 + q * 2]     = oA;
        out[(size_t)wid * 16 + q * 2 + 1] = oB;
    }
}

extern "C" void kernel_launch(void* const* d_in, const int* in_sizes, int n_in,
                              void* d_out, int out_size, void* d_ws, size_t ws_size,
                              hipStream_t stream) {
    const float* x  = (const float*)d_in[0];
    const void*  ei = d_in[1];
    const float* W1 = (const float*)d_in[2];
    const float* b1 = (const float*)d_in[3];
    const float* W2 = (const float*)d_in[4];
    const float* b2 = (const float*)d_in[5];

    int HID = in_sizes[3];            // 128
    int IN  = in_sizes[2] / HID;      // 128
    int OUT = in_sizes[4] / HID;      // 64
    int N   = in_sizes[0] / IN;       // 50000
    int E   = in_sizes[1] / 2;        // 800000
    int NB  = (N + 127) >> BSHIFT;    // dst buckets (391)
    int NC  = (E + CH - 1) / CH;      // chunks (391)

    char* p = (char*)d_ws;
    int* chist     = (int*)p;   p += align256((size_t)NB * NC * 4);
    int* btot      = (int*)p;   p += align256((size_t)NB * 4);
    int* bbase     = (int*)p;   p += align256((size_t)(NB + 1) * 4);
    int* rs_final  = (int*)p;   p += align256((size_t)(N + 1) * 4);
    int* esrc      = (int*)p;   p += align256((size_t)E * 4);
    float* dinv    = (float*)p; p += align256((size_t)N * 4);
    unsigned short* w1t = (unsigned short*)p; p += align256((size_t)HID * IN * 2);
    unsigned short* w2t = (unsigned short*)p; p += align256((size_t)OUT * HID * 2);
    // bbuf (E uint, dead after k_sort) overlays hb (N*HID bf16, written later)
    size_t hb_bytes = (size_t)N * HID * 2, bbuf_bytes = (size_t)E * 4;
    unsigned* bbuf = (unsigned*)p;
    unsigned short* hb = (unsigned short*)p;
    p += align256(hb_bytes > bbuf_bytes ? hb_bytes : bbuf_bytes);
    unsigned short* h1b = (unsigned short*)p; p += align256((size_t)N * HID * 2);
    unsigned short* h2b = (unsigned short*)p; p += align256((size_t)N * OUT * 2);

    // CSR build: hist -> btot -> bscan -> hscan2 -> bfill -> sort
    k_hist<<<NC + 2, 256, 0, stream>>>(ei, E, chist, NB, NC,
                                       W1, W2, w1t, w2t, IN, HID, HID, OUT);
    k_btot<<<(NB + 3) / 4, 256, 0, stream>>>(chist, btot, NB, NC);
    k_bscan<<<1, 1024, 0, stream>>>(btot, bbase, rs_final, NB, N);
    k_hscan2<<<(NB + 3) / 4, 256, 0, stream>>>(chist, bbase, NB, NC);
    k_bfill<<<NC, 256, 0, stream>>>(ei, E, chist, bbuf, NB, NC);
    k_sort<<<NB, 256, 0, stream>>>(bbuf, bbase, rs_final, dinv, esrc, N);

    // layer 1: hb = bf16(dinv * (x @ W1)) ; h1b = bf16(relu(dinv*sum + b1))
    k_gemm<128, true><<<(N + 63) / 64, 256, 0, stream>>>(x, w1t, dinv, hb, N, HID);
    k_agg128<<<(N + 3) / 4, 256, 0, stream>>>((const uint4*)hb, dinv, rs_final, esrc,
                                              b1, (uint4*)h1b, N);

    // layer 2: h2b = bf16(dinv * (h1b @ W2)) ; out = dinv*sum + b2
    k_gemm<64, false><<<(N + 63) / 64, 256, 0, stream>>>(h1b, w2t, dinv, h2b, N, OUT);
    k_agg64<<<(N + 3) / 4, 256, 0, stream>>>((const uint4*)h2b, dinv, rs_final, esrc,
                                             b2, (float4*)d_out, N);
}